// Round 2
// baseline (205.912 us; speedup 1.0000x reference)
//
#include <hip/hip_runtime.h>
#include <stdint.h>

typedef __attribute__((ext_vector_type(4))) float f32x4;
typedef __attribute__((ext_vector_type(8))) short bf16x8;
typedef __attribute__((ext_vector_type(4))) short bf16x4;

#define DEV static __device__ __forceinline__

DEV short f2bf(float f) {
  union { float f; uint32_t u; } x; x.f = f;
  uint32_t r = (x.u + 0x7fffu + ((x.u >> 16) & 1u)) >> 16;
  return (short)r;
}

DEV void gload16(const void* g, void* l) {
  __builtin_amdgcn_global_load_lds(
      (const __attribute__((address_space(1))) uint32_t*)g,
      (__attribute__((address_space(3))) uint32_t*)l, 16, 0, 0);
}

#define MFMA16(a, b, c) __builtin_amdgcn_mfma_f32_16x16x32_bf16((a), (b), (c), 0, 0, 0)

// ---------------- fp32 -> bf16 convert (x, y, Wq, Wkv, Wproj) ----------------
__global__ void convert_all(const float* __restrict__ x, const float* __restrict__ y,
                            const float* __restrict__ wq, const float* __restrict__ wkv,
                            const float* __restrict__ wp, short* __restrict__ ws)
{
  const long NX = 6291456L, NY = 6291456L, NQ = 589824L, NKV = 1179648L, NP = 589824L;
  short* xb = ws;
  short* yb = xb + NX;
  short* wqb = yb + NY;
  short* wkvb = wqb + NQ;
  short* wpb = wkvb + NKV;
  const long total4 = (NX + NY + NQ + NKV + NP) / 4;
  const long stride = (long)gridDim.x * blockDim.x;
  for (long i = (long)blockIdx.x * blockDim.x + threadIdx.x; i < total4; i += stride) {
    long e = i * 4;
    const float* src; short* dst; long off;
    if (e < NX)                 { src = x;   dst = xb;   off = e; }
    else if (e < NX + NY)       { src = y;   dst = yb;   off = e - NX; }
    else if (e < NX + NY + NQ)  { src = wq;  dst = wqb;  off = e - NX - NY; }
    else if (e < NX + NY + NQ + NKV) { src = wkv; dst = wkvb; off = e - NX - NY - NQ; }
    else                        { src = wp;  dst = wpb;  off = e - NX - NY - NQ - NKV; }
    const f32x4 v = *(const f32x4*)(src + off);
    bf16x4 o;
    o[0] = f2bf(v[0]); o[1] = f2bf(v[1]); o[2] = f2bf(v[2]); o[3] = f2bf(v[3]);
    *(bf16x4*)(dst + off) = o;
  }
}

// ---------------- fused QKV projection GEMM (+ l2norm for q/k, transpose for v) ----
// grid: (64, 18). bt<6: Q tiles; 6..11: K tiles; 12..17: V tiles. 128x128 tile, BK=64.
__global__ __launch_bounds__(256, 2) void qkv_gemm(
    const short* __restrict__ xb, const short* __restrict__ yb,
    const short* __restrict__ wqb, const short* __restrict__ wkvb,
    short* __restrict__ qb, short* __restrict__ kb, short* __restrict__ vT)
{
  __shared__ __align__(16) short sm[17408];   // lA(8192) + lB(8192); reused as lE 128x136
  __shared__ float sums[256];
  short* lA = sm;
  short* lB = sm + 8192;
  short* lE = sm;
  const int t = threadIdx.x;
  const int wv = t >> 6, lane = t & 63;
  const int c = lane & 15, g = lane >> 4;
  const int wm = wv >> 1, wn = wv & 1;
  const int bm = blockIdx.x, bt = blockIdx.y;

  const short* A; const short* W; int mode, h;
  if (bt < 6)       { A = xb; W = wqb  + (size_t)bt * 98304;                    mode = 0; h = bt; }
  else if (bt < 12) { A = yb; W = wkvb + (size_t)(bt - 6) * 98304;              mode = 1; h = bt - 6; }
  else              { A = yb; W = wkvb + (size_t)(589824 + (bt - 12) * 98304);  mode = 2; h = bt - 12; }

  const int am0 = bm * 128;
  const f32x4 z4 = {0.f, 0.f, 0.f, 0.f};
  f32x4 acc[4][4];
#pragma unroll
  for (int i = 0; i < 4; i++)
#pragma unroll
    for (int j = 0; j < 4; j++) acc[i][j] = z4;

  for (int kt = 0; kt < 768; kt += 64) {
    __syncthreads();
#pragma unroll
    for (int ch = 0; ch < 4; ch++) {
      const int obase = ch * 4096 + wv * 1024;   // wave-uniform byte base in 16KB tile
      const int o = obase + lane * 16;
      const int row = o >> 7, colb = o & 127;
      gload16((const char*)A + ((size_t)(am0 + row) * 768 + kt) * 2 + colb, (char*)lA + obase);
      gload16((const char*)W + ((size_t)row * 768 + kt) * 2 + colb, (char*)lB + obase);
    }
    __syncthreads();
#pragma unroll
    for (int kc = 0; kc < 2; kc++) {
      bf16x8 af[4], bfr[4];
#pragma unroll
      for (int mf = 0; mf < 4; mf++) af[mf]  = *(const bf16x8*)&lA[(wm*64 + mf*16 + c)*64 + kc*32 + g*8];
#pragma unroll
      for (int nf = 0; nf < 4; nf++) bfr[nf] = *(const bf16x8*)&lB[(wn*64 + nf*16 + c)*64 + kc*32 + g*8];
#pragma unroll
      for (int mf = 0; mf < 4; mf++)
#pragma unroll
        for (int nf = 0; nf < 4; nf++)
          acc[mf][nf] = MFMA16(af[mf], bfr[nf], acc[mf][nf]);
    }
  }
  __syncthreads();   // all LDS frag reads done; lE may reuse sm

  const int b = bm >> 3;
  const int nloc0 = (bm & 7) * 128;

  if (mode <= 1) {
    // fused row l2-norm over this head's 128 cols
#pragma unroll
    for (int mf = 0; mf < 4; mf++)
#pragma unroll
      for (int r = 0; r < 4; r++) {
        float s = 0.f;
#pragma unroll
        for (int nf = 0; nf < 4; nf++) { float v = acc[mf][nf][r]; s += v * v; }
        s += __shfl_xor(s, 1); s += __shfl_xor(s, 2);
        s += __shfl_xor(s, 4); s += __shfl_xor(s, 8);
        if (c == 0) sums[wn * 128 + wm * 64 + mf * 16 + 4 * g + r] = s;
      }
    __syncthreads();
    float sc[4][4];
#pragma unroll
    for (int mf = 0; mf < 4; mf++)
#pragma unroll
      for (int r = 0; r < 4; r++) {
        const int row = wm * 64 + mf * 16 + 4 * g + r;
        const float s = sums[row] + sums[128 + row];
        sc[mf][r] = 1.0f / fmaxf(sqrtf(s), 1e-12f);
      }
#pragma unroll
    for (int mf = 0; mf < 4; mf++)
#pragma unroll
      for (int nf = 0; nf < 4; nf++)
#pragma unroll
        for (int r = 0; r < 4; r++)
          lE[(wm*64 + mf*16 + 4*g + r) * 136 + wn*64 + nf*16 + c] = f2bf(acc[mf][nf][r] * sc[mf][r]);
    __syncthreads();
    short* dst = (mode == 0) ? qb : kb;
    const size_t base = ((size_t)(b * 6 + h) * 1024 + nloc0) * 128;
#pragma unroll
    for (int it = 0; it < 8; it++) {
      const int slot = it * 256 + t;
      const int row = slot >> 4, ch = slot & 15;
      bf16x8 v = *(const bf16x8*)&lE[row * 136 + ch * 8];
      *(bf16x8*)(dst + base + (size_t)row * 128 + ch * 8) = v;
    }
  } else {
    // V: transpose into lE[d][n1loc] (stride 136), then coalesced store to vT[bh][d][n1]
#pragma unroll
    for (int mf = 0; mf < 4; mf++)
#pragma unroll
      for (int nf = 0; nf < 4; nf++) {
        bf16x4 p;
#pragma unroll
        for (int r = 0; r < 4; r++) p[r] = f2bf(acc[mf][nf][r]);
        *(bf16x4*)&lE[(wn*64 + nf*16 + c) * 136 + wm*64 + mf*16 + 4*g] = p;
      }
    __syncthreads();
    const size_t base = ((size_t)(b * 6 + h) * 128) * 1024 + nloc0;
#pragma unroll
    for (int it = 0; it < 8; it++) {
      const int slot = it * 256 + t;
      const int d = slot >> 4, ch = slot & 15;
      bf16x8 v = *(const bf16x8*)&lE[d * 136 + ch * 8];
      *(bf16x8*)(vT + base + (size_t)d * 1024 + ch * 8) = v;
    }
  }
}

// ---------------- attention: per (b,h,qtile-128), 4 waves x 32 q rows --------------
// Logits = temp * cosine in [-|t|,|t|] -> no online max needed; sum-only softmax.
__global__ __launch_bounds__(256, 2) void attn_fwd(
    const short* __restrict__ qb, const short* __restrict__ kb,
    const short* __restrict__ vT, const float* __restrict__ temp,
    short* __restrict__ ob)
{
  __shared__ __align__(16) short pl[18432];   // 4 waves x 4608 (P tile 32x72 / O tile 32x136)
  const int t = threadIdx.x;
  const int wv = t >> 6, lane = t & 63;
  const int c = lane & 15, g = lane >> 4;
  const int qt = blockIdx.x, bh = blockIdx.y;
  const int b = bh / 6, h = bh % 6;
  short* myP = &pl[wv * 4608];

  const short* qbase = qb + (size_t)bh * 131072;
  const short* kbase = kb + (size_t)bh * 131072;
  const short* vbase = vT + (size_t)bh * 131072;
  const int q0 = qt * 128 + wv * 32;

  bf16x8 qf[2][4];   // hoisted Q fragments: 32 rows x 128 d
#pragma unroll
  for (int mf = 0; mf < 2; mf++)
#pragma unroll
    for (int dc = 0; dc < 4; dc++)
      qf[mf][dc] = *(const bf16x8*)(qbase + (size_t)(q0 + mf*16 + c) * 128 + dc*32 + g*8);

  const float t2 = temp[h] * 1.44269504088896341f;  // temp * log2(e)
  const f32x4 z4 = {0.f, 0.f, 0.f, 0.f};
  f32x4 oacc[2][8];
#pragma unroll
  for (int i = 0; i < 2; i++)
#pragma unroll
    for (int j = 0; j < 8; j++) oacc[i][j] = z4;
  float lsum[2][4] = {{0.f,0.f,0.f,0.f},{0.f,0.f,0.f,0.f}};

  for (int kt = 0; kt < 1024; kt += 64) {
    f32x4 s[2][4];
#pragma unroll
    for (int i = 0; i < 2; i++)
#pragma unroll
      for (int j = 0; j < 4; j++) s[i][j] = z4;
#pragma unroll
    for (int kf = 0; kf < 4; kf++) {
      bf16x8 kfr[4];
#pragma unroll
      for (int kc = 0; kc < 4; kc++)
        kfr[kc] = *(const bf16x8*)(kbase + (size_t)(kt + kf*16 + c) * 128 + kc*32 + g*8);
#pragma unroll
      for (int kc = 0; kc < 4; kc++) {
        s[0][kf] = MFMA16(qf[0][kc], kfr[kc], s[0][kf]);
        s[1][kf] = MFMA16(qf[1][kc], kfr[kc], s[1][kf]);
      }
    }
    // p = exp2(s * temp * log2e); per-lane partial row sums; P -> LDS (bf16)
#pragma unroll
    for (int mf = 0; mf < 2; mf++)
#pragma unroll
      for (int kf = 0; kf < 4; kf++)
#pragma unroll
        for (int r = 0; r < 4; r++) {
          float p = __builtin_amdgcn_exp2f(s[mf][kf][r] * t2);
          lsum[mf][r] += p;
          myP[(mf*16 + 4*g + r) * 72 + kf*16 + c] = f2bf(p);
        }
    // PV: A = P (from LDS), B = vT fragments (global, L2-resident)
#pragma unroll
    for (int kc = 0; kc < 2; kc++) {
      bf16x8 pa0 = *(const bf16x8*)&myP[(c)      * 72 + kc*32 + g*8];
      bf16x8 pa1 = *(const bf16x8*)&myP[(16 + c) * 72 + kc*32 + g*8];
#pragma unroll
      for (int df = 0; df < 8; df++) {
        bf16x8 vf = *(const bf16x8*)(vbase + (size_t)(df*16 + c) * 1024 + kt + kc*32 + g*8);
        oacc[0][df] = MFMA16(pa0, vf, oacc[0][df]);
        oacc[1][df] = MFMA16(pa1, vf, oacc[1][df]);
      }
    }
  }
  // finalize: row sums -> 1/sum, normalize O, stage via LDS, coalesced store
  float rin[2][4];
#pragma unroll
  for (int mf = 0; mf < 2; mf++)
#pragma unroll
    for (int r = 0; r < 4; r++) {
      float s = lsum[mf][r];
      s += __shfl_xor(s, 1); s += __shfl_xor(s, 2);
      s += __shfl_xor(s, 4); s += __shfl_xor(s, 8);
      rin[mf][r] = 1.0f / s;
    }
  short* myO = myP;  // reuse wave-private region as 32x136 out tile
#pragma unroll
  for (int mf = 0; mf < 2; mf++)
#pragma unroll
    for (int df = 0; df < 8; df++)
#pragma unroll
      for (int r = 0; r < 4; r++)
        myO[(mf*16 + 4*g + r) * 136 + df*16 + c] = f2bf(oacc[mf][df][r] * rin[mf][r]);
  const size_t obase_ = ((size_t)(b * 1024 + qt * 128 + wv * 32)) * 768 + h * 128;
#pragma unroll
  for (int it = 0; it < 8; it++) {
    const int slot = it * 64 + lane;
    const int row = slot >> 4, ch = slot & 15;
    bf16x8 v = *(const bf16x8*)&myO[row * 136 + ch * 8];
    *(bf16x8*)(ob + obase_ + (size_t)row * 768 + ch * 8) = v;
  }
}

// ---------------- output projection GEMM + bias (fp32 out) ------------------------
__global__ __launch_bounds__(256, 2) void proj_gemm(
    const short* __restrict__ ob, const short* __restrict__ wpb,
    const float* __restrict__ bias, float* __restrict__ out)
{
  __shared__ __align__(16) short sm[16384];
  short* lA = sm;
  short* lB = sm + 8192;
  const int t = threadIdx.x;
  const int wv = t >> 6, lane = t & 63;
  const int c = lane & 15, g = lane >> 4;
  const int wm = wv >> 1, wn = wv & 1;
  const int bm = blockIdx.x, bn = blockIdx.y;
  const short* W = wpb + (size_t)bn * 98304;
  const int am0 = bm * 128;
  const f32x4 z4 = {0.f, 0.f, 0.f, 0.f};
  f32x4 acc[4][4];
#pragma unroll
  for (int i = 0; i < 4; i++)
#pragma unroll
    for (int j = 0; j < 4; j++) acc[i][j] = z4;

  for (int kt = 0; kt < 768; kt += 64) {
    __syncthreads();
#pragma unroll
    for (int ch = 0; ch < 4; ch++) {
      const int obase = ch * 4096 + wv * 1024;
      const int o = obase + lane * 16;
      const int row = o >> 7, colb = o & 127;
      gload16((const char*)ob + ((size_t)(am0 + row) * 768 + kt) * 2 + colb, (char*)lA + obase);
      gload16((const char*)W  + ((size_t)row * 768 + kt) * 2 + colb, (char*)lB + obase);
    }
    __syncthreads();
#pragma unroll
    for (int kc = 0; kc < 2; kc++) {
      bf16x8 af[4], bfr[4];
#pragma unroll
      for (int mf = 0; mf < 4; mf++) af[mf]  = *(const bf16x8*)&lA[(wm*64 + mf*16 + c)*64 + kc*32 + g*8];
#pragma unroll
      for (int nf = 0; nf < 4; nf++) bfr[nf] = *(const bf16x8*)&lB[(wn*64 + nf*16 + c)*64 + kc*32 + g*8];
#pragma unroll
      for (int mf = 0; mf < 4; mf++)
#pragma unroll
        for (int nf = 0; nf < 4; nf++)
          acc[mf][nf] = MFMA16(af[mf], bfr[nf], acc[mf][nf]);
    }
  }
  float bb[4];
#pragma unroll
  for (int nf = 0; nf < 4; nf++) bb[nf] = bias[bn*128 + wn*64 + nf*16 + c];
#pragma unroll
  for (int mf = 0; mf < 4; mf++)
#pragma unroll
    for (int nf = 0; nf < 4; nf++)
#pragma unroll
      for (int r = 0; r < 4; r++)
        out[(size_t)(am0 + wm*64 + mf*16 + 4*g + r) * 768 + bn*128 + wn*64 + nf*16 + c]
            = acc[mf][nf][r] + bb[nf];
}

extern "C" void kernel_launch(void* const* d_in, const int* in_sizes, int n_in,
                              void* d_out, int out_size, void* d_ws, size_t ws_size,
                              hipStream_t stream) {
  const float* x    = (const float*)d_in[0];
  const float* y    = (const float*)d_in[1];
  const float* wq   = (const float*)d_in[2];
  const float* wkv  = (const float*)d_in[3];
  const float* wp   = (const float*)d_in[4];
  const float* bias = (const float*)d_in[5];
  const float* temp = (const float*)d_in[6];

  short* ws   = (short*)d_ws;
  short* xb   = ws;
  short* yb   = xb + 6291456;
  short* wqb  = yb + 6291456;
  short* wkvb = wqb + 589824;
  short* wpb  = wkvb + 1179648;
  short* qb   = wpb + 589824;
  short* kb   = qb + 6291456;
  short* vT   = kb + 6291456;
  short* ob   = vT + 6291456;

  convert_all<<<dim3(1024), dim3(256), 0, stream>>>(x, y, wq, wkv, wp, ws);
  qkv_gemm<<<dim3(64, 18), dim3(256), 0, stream>>>(xb, yb, wqb, wkvb, qb, kb, vT);
  attn_fwd<<<dim3(8, 48), dim3(256), 0, stream>>>(qb, kb, vT, temp, ob);
  proj_gemm<<<dim3(64, 6), dim3(256), 0, stream>>>(ob, wpb, bias, (float*)d_out);
}

// Round 3
// 133.455 us; speedup vs baseline: 1.5429x; 1.5429x over previous
//
#include <hip/hip_runtime.h>
#include <stdint.h>

typedef __attribute__((ext_vector_type(4))) float f32x4;
typedef __attribute__((ext_vector_type(8))) short bf16x8;
typedef __attribute__((ext_vector_type(4))) short bf16x4;

#define DEV static __device__ __forceinline__

DEV short f2bf(float f) {
  union { float f; uint32_t u; } x; x.f = f;
  uint32_t r = (x.u + 0x7fffu + ((x.u >> 16) & 1u)) >> 16;
  return (short)r;
}

DEV void gload16(const void* g, void* l) {
  __builtin_amdgcn_global_load_lds(
      (const __attribute__((address_space(1))) uint32_t*)g,
      (__attribute__((address_space(3))) uint32_t*)l, 16, 0, 0);
}

#define MFMA16(a, b, c) __builtin_amdgcn_mfma_f32_16x16x32_bf16((a), (b), (c), 0, 0, 0)

// ---------------- fp32 -> bf16 convert (x, y, Wq, Wkv, Wproj) ----------------
__global__ void convert_all(const float* __restrict__ x, const float* __restrict__ y,
                            const float* __restrict__ wq, const float* __restrict__ wkv,
                            const float* __restrict__ wp, short* __restrict__ ws)
{
  const long NX = 6291456L, NY = 6291456L, NQ = 589824L, NKV = 1179648L, NP = 589824L;
  short* xb = ws;
  short* yb = xb + NX;
  short* wqb = yb + NY;
  short* wkvb = wqb + NQ;
  short* wpb = wkvb + NKV;
  const long total4 = (NX + NY + NQ + NKV + NP) / 4;
  const long stride = (long)gridDim.x * blockDim.x;
  for (long i = (long)blockIdx.x * blockDim.x + threadIdx.x; i < total4; i += stride) {
    long e = i * 4;
    const float* src; short* dst; long off;
    if (e < NX)                 { src = x;   dst = xb;   off = e; }
    else if (e < NX + NY)       { src = y;   dst = yb;   off = e - NX; }
    else if (e < NX + NY + NQ)  { src = wq;  dst = wqb;  off = e - NX - NY; }
    else if (e < NX + NY + NQ + NKV) { src = wkv; dst = wkvb; off = e - NX - NY - NQ; }
    else                        { src = wp;  dst = wpb;  off = e - NX - NY - NQ - NKV; }
    const f32x4 v = *(const f32x4*)(src + off);
    bf16x4 o;
    o[0] = f2bf(v[0]); o[1] = f2bf(v[1]); o[2] = f2bf(v[2]); o[3] = f2bf(v[3]);
    *(bf16x4*)(dst + off) = o;
  }
}

// ---------------- fused QKV projection GEMM (+ l2norm for q/k, transpose for v) ----
// grid: (64, 18). bt<6: Q tiles; 6..11: K tiles; 12..17: V tiles. 128x128 tile, BK=64.
__global__ __launch_bounds__(256, 2) void qkv_gemm(
    const short* __restrict__ xb, const short* __restrict__ yb,
    const short* __restrict__ wqb, const short* __restrict__ wkvb,
    short* __restrict__ qb, short* __restrict__ kb, short* __restrict__ vT)
{
  __shared__ __align__(16) short sm[17408];   // lA(8192) + lB(8192); reused as lE 128x136
  __shared__ float sums[256];
  short* lA = sm;
  short* lB = sm + 8192;
  short* lE = sm;
  const int t = threadIdx.x;
  const int wv = t >> 6, lane = t & 63;
  const int c = lane & 15, g = lane >> 4;
  const int wm = wv >> 1, wn = wv & 1;
  const int bm = blockIdx.x, bt = blockIdx.y;

  const short* A; const short* W; int mode, h;
  if (bt < 6)       { A = xb; W = wqb  + (size_t)bt * 98304;                    mode = 0; h = bt; }
  else if (bt < 12) { A = yb; W = wkvb + (size_t)(bt - 6) * 98304;              mode = 1; h = bt - 6; }
  else              { A = yb; W = wkvb + (size_t)(589824 + (bt - 12) * 98304);  mode = 2; h = bt - 12; }

  const int am0 = bm * 128;
  const f32x4 z4 = {0.f, 0.f, 0.f, 0.f};
  f32x4 acc[4][4];
#pragma unroll
  for (int i = 0; i < 4; i++)
#pragma unroll
    for (int j = 0; j < 4; j++) acc[i][j] = z4;

  for (int kt = 0; kt < 768; kt += 64) {
    __syncthreads();
#pragma unroll
    for (int ch = 0; ch < 4; ch++) {
      const int obase = ch * 4096 + wv * 1024;   // wave-uniform byte base in 16KB tile
      const int o = obase + lane * 16;
      const int row = o >> 7, colb = o & 127;
      gload16((const char*)A + ((size_t)(am0 + row) * 768 + kt) * 2 + colb, (char*)lA + obase);
      gload16((const char*)W + ((size_t)row * 768 + kt) * 2 + colb, (char*)lB + obase);
    }
    __syncthreads();
#pragma unroll
    for (int kc = 0; kc < 2; kc++) {
      bf16x8 af[4], bfr[4];
#pragma unroll
      for (int mf = 0; mf < 4; mf++) af[mf]  = *(const bf16x8*)&lA[(wm*64 + mf*16 + c)*64 + kc*32 + g*8];
#pragma unroll
      for (int nf = 0; nf < 4; nf++) bfr[nf] = *(const bf16x8*)&lB[(wn*64 + nf*16 + c)*64 + kc*32 + g*8];
#pragma unroll
      for (int mf = 0; mf < 4; mf++)
#pragma unroll
        for (int nf = 0; nf < 4; nf++)
          acc[mf][nf] = MFMA16(af[mf], bfr[nf], acc[mf][nf]);
    }
  }
  __syncthreads();   // all LDS frag reads done; lE may reuse sm

  const int b = bm >> 3;
  const int nloc0 = (bm & 7) * 128;

  if (mode <= 1) {
    // fused row l2-norm over this head's 128 cols
#pragma unroll
    for (int mf = 0; mf < 4; mf++)
#pragma unroll
      for (int r = 0; r < 4; r++) {
        float s = 0.f;
#pragma unroll
        for (int nf = 0; nf < 4; nf++) { float v = acc[mf][nf][r]; s += v * v; }
        s += __shfl_xor(s, 1); s += __shfl_xor(s, 2);
        s += __shfl_xor(s, 4); s += __shfl_xor(s, 8);
        if (c == 0) sums[wn * 128 + wm * 64 + mf * 16 + 4 * g + r] = s;
      }
    __syncthreads();
    float sc[4][4];
#pragma unroll
    for (int mf = 0; mf < 4; mf++)
#pragma unroll
      for (int r = 0; r < 4; r++) {
        const int row = wm * 64 + mf * 16 + 4 * g + r;
        const float s = sums[row] + sums[128 + row];
        sc[mf][r] = 1.0f / fmaxf(sqrtf(s), 1e-12f);
      }
#pragma unroll
    for (int mf = 0; mf < 4; mf++)
#pragma unroll
      for (int nf = 0; nf < 4; nf++)
#pragma unroll
        for (int r = 0; r < 4; r++)
          lE[(wm*64 + mf*16 + 4*g + r) * 136 + wn*64 + nf*16 + c] = f2bf(acc[mf][nf][r] * sc[mf][r]);
    __syncthreads();
    short* dst = (mode == 0) ? qb : kb;
    const size_t base = ((size_t)(b * 6 + h) * 1024 + nloc0) * 128;
#pragma unroll
    for (int it = 0; it < 8; it++) {
      const int slot = it * 256 + t;
      const int row = slot >> 4, ch = slot & 15;
      bf16x8 v = *(const bf16x8*)&lE[row * 136 + ch * 8];
      *(bf16x8*)(dst + base + (size_t)row * 128 + ch * 8) = v;
    }
  } else {
    // V: transpose into lE[d][n1loc] (stride 136), then coalesced store to vT[bh][d][n1]
#pragma unroll
    for (int mf = 0; mf < 4; mf++)
#pragma unroll
      for (int nf = 0; nf < 4; nf++) {
        bf16x4 p;
#pragma unroll
        for (int r = 0; r < 4; r++) p[r] = f2bf(acc[mf][nf][r]);
        *(bf16x4*)&lE[(wn*64 + nf*16 + c) * 136 + wm*64 + mf*16 + 4*g] = p;
      }
    __syncthreads();
    const size_t base = ((size_t)(b * 6 + h) * 128) * 1024 + nloc0;
#pragma unroll
    for (int it = 0; it < 8; it++) {
      const int slot = it * 256 + t;
      const int d = slot >> 4, ch = slot & 15;
      bf16x8 v = *(const bf16x8*)&lE[d * 136 + ch * 8];
      *(bf16x8*)(vT + base + (size_t)d * 1024 + ch * 8) = v;
    }
  }
}

// ---------------- attention v2: LDS-staged K/V with XOR swizzle --------------------
// grid (16, 48): 64-row q-tile, 2 waves x 32 rows; 768 blocks = 3/CU (LDS 49KB).
// K tile [64][128] bf16, swz byte ^= ((row&7)<<4); V^T tile [128][64] bf16, same swz.
__global__ __launch_bounds__(128, 2) void attn_fwd(
    const short* __restrict__ qb, const short* __restrict__ kb,
    const short* __restrict__ vT, const float* __restrict__ temp,
    short* __restrict__ ob)
{
  __shared__ __align__(16) char lds[50176];
  char* kbuf = lds;            // 16384B: [64 n][256B swz]
  char* vbuf = lds + 16384;    // 16384B: [128 d][128B swz]
  char* pl   = lds + 32768;    // 2 waves x 8704B (P 32x72 shorts / O 32x136 shorts)
  const int t = threadIdx.x;
  const int wv = t >> 6, lane = t & 63;
  const int c = lane & 15, g = lane >> 4;
  const int qt = blockIdx.x, bh = blockIdx.y;
  const int b = bh / 6, h = bh % 6;
  short* myP = (short*)(pl + wv * 8704);

  const short* qbase = qb + (size_t)bh * 131072;
  const char*  kgl   = (const char*)(kb + (size_t)bh * 131072);
  const char*  vgl   = (const char*)(vT + (size_t)bh * 131072);
  const int q0 = qt * 64 + wv * 32;

  bf16x8 qf[2][4];   // hoisted Q: 32 rows x 128 d per wave
#pragma unroll
  for (int mf = 0; mf < 2; mf++)
#pragma unroll
    for (int dc = 0; dc < 4; dc++)
      qf[mf][dc] = *(const bf16x8*)(qbase + (size_t)(q0 + mf*16 + c) * 128 + dc*32 + g*8);

  const float t2 = temp[h] * 1.44269504088896341f;  // temp * log2(e)
  const f32x4 z4 = {0.f, 0.f, 0.f, 0.f};
  f32x4 oacc[2][8];
#pragma unroll
  for (int i = 0; i < 2; i++)
#pragma unroll
    for (int j = 0; j < 8; j++) oacc[i][j] = z4;
  float lsum[2][4] = {{0.f,0.f,0.f,0.f},{0.f,0.f,0.f,0.f}};

  for (int kt = 0; kt < 1024; kt += 64) {
    __syncthreads();   // previous tile fully consumed
    // stage K: each wave does 8KB; pre-swizzled global source, linear LDS dest
#pragma unroll
    for (int i = 0; i < 8; i++) {
      const int o = wv * 8192 + i * 1024 + lane * 16;
      const int row = o >> 8;
      const int cb = (o & 255) ^ ((row & 7) << 4);
      gload16(kgl + (size_t)(kt + row) * 256 + cb, kbuf + wv * 8192 + i * 1024);
    }
    // stage V^T: rows are d (128B each)
#pragma unroll
    for (int i = 0; i < 8; i++) {
      const int o = wv * 8192 + i * 1024 + lane * 16;
      const int d = o >> 7;
      const int cb = (o & 127) ^ ((d & 7) << 4);
      gload16(vgl + (size_t)d * 2048 + (size_t)kt * 2 + cb, vbuf + wv * 8192 + i * 1024);
    }
    __syncthreads();   // staged tile visible (vmcnt drained by barrier)

    // QK^T from LDS K (swizzled read)
    f32x4 s[2][4];
#pragma unroll
    for (int i = 0; i < 2; i++)
#pragma unroll
      for (int j = 0; j < 4; j++) s[i][j] = z4;
#pragma unroll
    for (int kf = 0; kf < 4; kf++) {
      bf16x8 kfr[4];
#pragma unroll
      for (int kc = 0; kc < 4; kc++) {
        const int row = kf * 16 + c;
        const int cb = (kc * 64 + g * 16) ^ ((row & 7) << 4);
        kfr[kc] = *(const bf16x8*)(kbuf + row * 256 + cb);
      }
      __builtin_amdgcn_s_setprio(1);
#pragma unroll
      for (int kc = 0; kc < 4; kc++) {
        s[0][kf] = MFMA16(qf[0][kc], kfr[kc], s[0][kf]);
        s[1][kf] = MFMA16(qf[1][kc], kfr[kc], s[1][kf]);
      }
      __builtin_amdgcn_s_setprio(0);
    }
    // p = exp2(s * t2); partial row sums; P -> wave-private LDS (stride 72 shorts)
#pragma unroll
    for (int mf = 0; mf < 2; mf++)
#pragma unroll
      for (int kf = 0; kf < 4; kf++)
#pragma unroll
        for (int r = 0; r < 4; r++) {
          float p = __builtin_amdgcn_exp2f(s[mf][kf][r] * t2);
          lsum[mf][r] += p;
          myP[(mf*16 + 4*g + r) * 72 + kf*16 + c] = f2bf(p);
        }
    // PV: A = P (LDS), B = V^T fragments (LDS, swizzled read)
#pragma unroll
    for (int kc = 0; kc < 2; kc++) {
      bf16x8 pa0 = *(const bf16x8*)&myP[(c)      * 72 + kc*32 + g*8];
      bf16x8 pa1 = *(const bf16x8*)&myP[(16 + c) * 72 + kc*32 + g*8];
      __builtin_amdgcn_s_setprio(1);
#pragma unroll
      for (int df = 0; df < 8; df++) {
        const int d = df * 16 + c;
        const int cb = (kc * 64 + g * 16) ^ ((d & 7) << 4);
        bf16x8 vf = *(const bf16x8*)(vbuf + d * 128 + cb);
        oacc[0][df] = MFMA16(pa0, vf, oacc[0][df]);
        oacc[1][df] = MFMA16(pa1, vf, oacc[1][df]);
      }
      __builtin_amdgcn_s_setprio(0);
    }
  }
  // finalize: row sums -> 1/sum, normalize O, stage via LDS, coalesced store
  float rin[2][4];
#pragma unroll
  for (int mf = 0; mf < 2; mf++)
#pragma unroll
    for (int r = 0; r < 4; r++) {
      float s = lsum[mf][r];
      s += __shfl_xor(s, 1); s += __shfl_xor(s, 2);
      s += __shfl_xor(s, 4); s += __shfl_xor(s, 8);
      rin[mf][r] = 1.0f / s;
    }
  short* myO = myP;  // reuse wave-private region as 32x136 out tile
#pragma unroll
  for (int mf = 0; mf < 2; mf++)
#pragma unroll
    for (int df = 0; df < 8; df++)
#pragma unroll
      for (int r = 0; r < 4; r++)
        myO[(mf*16 + 4*g + r) * 136 + df*16 + c] = f2bf(oacc[mf][df][r] * rin[mf][r]);
  const size_t obase_ = ((size_t)(b * 1024 + q0)) * 768 + h * 128;
#pragma unroll
  for (int it = 0; it < 8; it++) {
    const int slot = it * 64 + lane;
    const int row = slot >> 4, ch = slot & 15;
    bf16x8 v = *(const bf16x8*)&myO[row * 136 + ch * 8];
    *(bf16x8*)(ob + obase_ + (size_t)row * 768 + ch * 8) = v;
  }
}

// ---------------- output projection GEMM + bias (fp32 out) ------------------------
__global__ __launch_bounds__(256, 2) void proj_gemm(
    const short* __restrict__ ob, const short* __restrict__ wpb,
    const float* __restrict__ bias, float* __restrict__ out)
{
  __shared__ __align__(16) short sm[16384];
  short* lA = sm;
  short* lB = sm + 8192;
  const int t = threadIdx.x;
  const int wv = t >> 6, lane = t & 63;
  const int c = lane & 15, g = lane >> 4;
  const int wm = wv >> 1, wn = wv & 1;
  const int bm = blockIdx.x, bn = blockIdx.y;
  const short* W = wpb + (size_t)bn * 98304;
  const int am0 = bm * 128;
  const f32x4 z4 = {0.f, 0.f, 0.f, 0.f};
  f32x4 acc[4][4];
#pragma unroll
  for (int i = 0; i < 4; i++)
#pragma unroll
    for (int j = 0; j < 4; j++) acc[i][j] = z4;

  for (int kt = 0; kt < 768; kt += 64) {
    __syncthreads();
#pragma unroll
    for (int ch = 0; ch < 4; ch++) {
      const int obase = ch * 4096 + wv * 1024;
      const int o = obase + lane * 16;
      const int row = o >> 7, colb = o & 127;
      gload16((const char*)ob + ((size_t)(am0 + row) * 768 + kt) * 2 + colb, (char*)lA + obase);
      gload16((const char*)W  + ((size_t)row * 768 + kt) * 2 + colb, (char*)lB + obase);
    }
    __syncthreads();
#pragma unroll
    for (int kc = 0; kc < 2; kc++) {
      bf16x8 af[4], bfr[4];
#pragma unroll
      for (int mf = 0; mf < 4; mf++) af[mf]  = *(const bf16x8*)&lA[(wm*64 + mf*16 + c)*64 + kc*32 + g*8];
#pragma unroll
      for (int nf = 0; nf < 4; nf++) bfr[nf] = *(const bf16x8*)&lB[(wn*64 + nf*16 + c)*64 + kc*32 + g*8];
#pragma unroll
      for (int mf = 0; mf < 4; mf++)
#pragma unroll
        for (int nf = 0; nf < 4; nf++)
          acc[mf][nf] = MFMA16(af[mf], bfr[nf], acc[mf][nf]);
    }
  }
  float bb[4];
#pragma unroll
  for (int nf = 0; nf < 4; nf++) bb[nf] = bias[bn*128 + wn*64 + nf*16 + c];
#pragma unroll
  for (int mf = 0; mf < 4; mf++)
#pragma unroll
    for (int nf = 0; nf < 4; nf++)
#pragma unroll
      for (int r = 0; r < 4; r++)
        out[(size_t)(am0 + wm*64 + mf*16 + 4*g + r) * 768 + bn*128 + wn*64 + nf*16 + c]
            = acc[mf][nf][r] + bb[nf];
}

extern "C" void kernel_launch(void* const* d_in, const int* in_sizes, int n_in,
                              void* d_out, int out_size, void* d_ws, size_t ws_size,
                              hipStream_t stream) {
  const float* x    = (const float*)d_in[0];
  const float* y    = (const float*)d_in[1];
  const float* wq   = (const float*)d_in[2];
  const float* wkv  = (const float*)d_in[3];
  const float* wp   = (const float*)d_in[4];
  const float* bias = (const float*)d_in[5];
  const float* temp = (const float*)d_in[6];

  short* ws   = (short*)d_ws;
  short* xb   = ws;
  short* yb   = xb + 6291456;
  short* wqb  = yb + 6291456;
  short* wkvb = wqb + 589824;
  short* wpb  = wkvb + 1179648;
  short* qb   = wpb + 589824;
  short* kb   = qb + 6291456;
  short* vT   = kb + 6291456;
  short* ob   = vT + 6291456;

  convert_all<<<dim3(1024), dim3(256), 0, stream>>>(x, y, wq, wkv, wp, ws);
  qkv_gemm<<<dim3(64, 18), dim3(256), 0, stream>>>(xb, yb, wqb, wkvb, qb, kb, vT);
  attn_fwd<<<dim3(16, 48), dim3(128), 0, stream>>>(qb, kb, vT, temp, ob);
  proj_gemm<<<dim3(64, 6), dim3(256), 0, stream>>>(ob, wpb, bias, (float*)d_out);
}

// Round 8
// 126.935 us; speedup vs baseline: 1.6222x; 1.0514x over previous
//
#include <hip/hip_runtime.h>
#include <stdint.h>

typedef __attribute__((ext_vector_type(4))) float f32x4;
typedef __attribute__((ext_vector_type(8))) short bf16x8;
typedef __attribute__((ext_vector_type(4))) short bf16x4;

#define DEV static __device__ __forceinline__

DEV short f2bf(float f) {
  union { float f; uint32_t u; } x; x.f = f;
  uint32_t r = (x.u + 0x7fffu + ((x.u >> 16) & 1u)) >> 16;
  return (short)r;
}

DEV void gload16(const void* g, void* l) {
  __builtin_amdgcn_global_load_lds(
      (const __attribute__((address_space(1))) uint32_t*)g,
      (__attribute__((address_space(3))) uint32_t*)l, 16, 0, 0);
}

#define MFMA16(a, b, c) __builtin_amdgcn_mfma_f32_16x16x32_bf16((a), (b), (c), 0, 0, 0)
#define WAITV(n) asm volatile("s_waitcnt vmcnt(" #n ")" ::: "memory")
#define BAR() __builtin_amdgcn_s_barrier()

// ---------------- fp32 -> bf16 convert (x, y, Wq, Wkv, Wproj) ----------------
__global__ void convert_all(const float* __restrict__ x, const float* __restrict__ y,
                            const float* __restrict__ wq, const float* __restrict__ wkv,
                            const float* __restrict__ wp, short* __restrict__ ws)
{
  const long NX = 6291456L, NY = 6291456L, NQ = 589824L, NKV = 1179648L, NP = 589824L;
  short* xb = ws;
  short* yb = xb + NX;
  short* wqb = yb + NY;
  short* wkvb = wqb + NQ;
  short* wpb = wkvb + NKV;
  const long total4 = (NX + NY + NQ + NKV + NP) / 4;
  const long stride = (long)gridDim.x * blockDim.x;
  for (long i = (long)blockIdx.x * blockDim.x + threadIdx.x; i < total4; i += stride) {
    long e = i * 4;
    const float* src; short* dst; long off;
    if (e < NX)                 { src = x;   dst = xb;   off = e; }
    else if (e < NX + NY)       { src = y;   dst = yb;   off = e - NX; }
    else if (e < NX + NY + NQ)  { src = wq;  dst = wqb;  off = e - NX - NY; }
    else if (e < NX + NY + NQ + NKV) { src = wkv; dst = wkvb; off = e - NX - NY - NQ; }
    else                        { src = wp;  dst = wpb;  off = e - NX - NY - NQ - NKV; }
    const f32x4 v = *(const f32x4*)(src + off);
    bf16x4 o;
    o[0] = f2bf(v[0]); o[1] = f2bf(v[1]); o[2] = f2bf(v[2]); o[3] = f2bf(v[3]);
    *(bf16x4*)(dst + off) = o;
  }
}

// ---------------- fused QKV projection GEMM v2: dbuf + counted vmcnt + T2 swizzle --
// grid: (64, 18). 128x128 tile, BK=64, 12 K-steps. LDS: 2 x (lA 16KB + lB 16KB).
// STAGE = 8 loads/thread (16 wave-chunks x 1024B per buffer) -> WAITV(8).
__global__ __launch_bounds__(256, 2) void qkv_gemm(
    const short* __restrict__ xb, const short* __restrict__ yb,
    const short* __restrict__ wqb, const short* __restrict__ wkvb,
    short* __restrict__ qb, short* __restrict__ kb, short* __restrict__ vT)
{
  __shared__ __align__(16) char lds[65536];   // dbuf staging; reused as lE (34816B)
  __shared__ float sums[256];
  short* lE = (short*)lds;
  const int t = threadIdx.x;
  const int wv = t >> 6, lane = t & 63;
  const int c = lane & 15, g = lane >> 4;
  const int wm = wv >> 1, wn = wv & 1;
  const int bm = blockIdx.x, bt = blockIdx.y;

  const short* A; const short* W; int mode, h;
  if (bt < 6)       { A = xb; W = wqb  + (size_t)bt * 98304;                    mode = 0; h = bt; }
  else if (bt < 12) { A = yb; W = wkvb + (size_t)(bt - 6) * 98304;              mode = 1; h = bt - 6; }
  else              { A = yb; W = wkvb + (size_t)(589824 + (bt - 12) * 98304);  mode = 2; h = bt - 12; }

  const int am0 = bm * 128;
  const f32x4 z4 = {0.f, 0.f, 0.f, 0.f};
  f32x4 acc[4][4];
#pragma unroll
  for (int i = 0; i < 4; i++)
#pragma unroll
    for (int j = 0; j < 4; j++) acc[i][j] = z4;

  // stage tile kt into parity p (pre-swizzled source, linear LDS dest)
  auto STAGE = [&](int kt, int p) {
    char* lA = lds + p * 32768;
    char* lB = lA + 16384;
#pragma unroll
    for (int i = 0; i < 4; i++) {
      const int ob = (i * 4 + wv) * 1024;           // wave-uniform; 16 x 1024B = 16KB
      const int o = ob + lane * 16;
      const int row = o >> 7;
      const int cb = (o & 127) ^ ((row & 7) << 4);
      gload16((const char*)A + ((size_t)(am0 + row) * 768 + kt) * 2 + cb, lA + ob);
      gload16((const char*)W + ((size_t)row * 768 + kt) * 2 + cb, lB + ob);
    }
  };
  auto COMPUTE = [&](int p) {
    char* lA = lds + p * 32768;
    char* lB = lA + 16384;
#pragma unroll
    for (int kc = 0; kc < 2; kc++) {
      bf16x8 af[4], bfr[4];
#pragma unroll
      for (int mf = 0; mf < 4; mf++) {
        const int row = wm * 64 + mf * 16 + c;
        af[mf] = *(const bf16x8*)(lA + row * 128 + ((kc * 64 + g * 16) ^ ((row & 7) << 4)));
      }
#pragma unroll
      for (int nf = 0; nf < 4; nf++) {
        const int row = wn * 64 + nf * 16 + c;
        bfr[nf] = *(const bf16x8*)(lB + row * 128 + ((kc * 64 + g * 16) ^ ((row & 7) << 4)));
      }
      __builtin_amdgcn_s_setprio(1);
#pragma unroll
      for (int mf = 0; mf < 4; mf++)
#pragma unroll
        for (int nf = 0; nf < 4; nf++)
          acc[mf][nf] = MFMA16(af[mf], bfr[nf], acc[mf][nf]);
      __builtin_amdgcn_s_setprio(0);
    }
  };

  STAGE(0, 0);
  WAITV(0); BAR();
  for (int kt = 0; kt < 11; kt++) {
    STAGE((kt + 1) * 64, (kt + 1) & 1);
    WAITV(8); BAR();
    COMPUTE(kt & 1);
    BAR();
  }
  WAITV(0); BAR();
  COMPUTE(1);
  __syncthreads();   // all frag reads done; lE may reuse lds

  const int b = bm >> 3;
  const int nloc0 = (bm & 7) * 128;

  if (mode <= 1) {
    // fused row l2-norm over this head's 128 cols
#pragma unroll
    for (int mf = 0; mf < 4; mf++)
#pragma unroll
      for (int r = 0; r < 4; r++) {
        float s = 0.f;
#pragma unroll
        for (int nf = 0; nf < 4; nf++) { float v = acc[mf][nf][r]; s += v * v; }
        s += __shfl_xor(s, 1); s += __shfl_xor(s, 2);
        s += __shfl_xor(s, 4); s += __shfl_xor(s, 8);
        if (c == 0) sums[wn * 128 + wm * 64 + mf * 16 + 4 * g + r] = s;
      }
    __syncthreads();
    float sc[4][4];
#pragma unroll
    for (int mf = 0; mf < 4; mf++)
#pragma unroll
      for (int r = 0; r < 4; r++) {
        const int row = wm * 64 + mf * 16 + 4 * g + r;
        const float s = sums[row] + sums[128 + row];
        sc[mf][r] = 1.0f / fmaxf(sqrtf(s), 1e-12f);
      }
#pragma unroll
    for (int mf = 0; mf < 4; mf++)
#pragma unroll
      for (int nf = 0; nf < 4; nf++)
#pragma unroll
        for (int r = 0; r < 4; r++)
          lE[(wm*64 + mf*16 + 4*g + r) * 136 + wn*64 + nf*16 + c] = f2bf(acc[mf][nf][r] * sc[mf][r]);
    __syncthreads();
    short* dst = (mode == 0) ? qb : kb;
    const size_t base = ((size_t)(b * 6 + h) * 1024 + nloc0) * 128;
#pragma unroll
    for (int it = 0; it < 8; it++) {
      const int slot = it * 256 + t;
      const int row = slot >> 4, ch = slot & 15;
      bf16x8 v = *(const bf16x8*)&lE[row * 136 + ch * 8];
      *(bf16x8*)(dst + base + (size_t)row * 128 + ch * 8) = v;
    }
  } else {
    // V: transpose into lE[d][n1loc] (stride 136), then coalesced store to vT[bh][d][n1]
#pragma unroll
    for (int mf = 0; mf < 4; mf++)
#pragma unroll
      for (int nf = 0; nf < 4; nf++) {
        bf16x4 p;
#pragma unroll
        for (int r = 0; r < 4; r++) p[r] = f2bf(acc[mf][nf][r]);
        *(bf16x4*)&lE[(wn*64 + nf*16 + c) * 136 + wm*64 + mf*16 + 4*g] = p;
      }
    __syncthreads();
    const size_t base = ((size_t)(b * 6 + h) * 128) * 1024 + nloc0;
#pragma unroll
    for (int it = 0; it < 8; it++) {
      const int slot = it * 256 + t;
      const int d = slot >> 4, ch = slot & 15;
      bf16x8 v = *(const bf16x8*)&lE[d * 136 + ch * 8];
      *(bf16x8*)(vT + base + (size_t)d * 1024 + ch * 8) = v;
    }
  }
}

// ---------------- attention v3: KVBLK=32 double-buffer + counted vmcnt + XCD swz ---
// 768 blocks (1-D), 128 thr. XCD-swizzle: each XCD owns 6 complete bh (K/V L2-res).
// LDS 37888: 2 x (K 8KB + V 8KB) dbuf + 2 waves x 2560B P (32 rows x 80B).
// STAGE = 8 loads/thread (full 8KB coverage per buffer); in-loop WAITV(8).
__global__ __launch_bounds__(128, 2) void attn_fwd(
    const short* __restrict__ qb, const short* __restrict__ kb,
    const short* __restrict__ vT, const float* __restrict__ temp,
    short* __restrict__ ob)
{
  __shared__ __align__(16) char lds[37888];
  const int t = threadIdx.x;
  const int wv = t >> 6, lane = t & 63;
  const int c = lane & 15, g = lane >> 4;
  const int bid = blockIdx.x;
  const int work = (bid & 7) * 96 + (bid >> 3);   // bijective: 768 = 8 XCD x 96
  const int bh = work >> 4, qt = work & 15;
  const int b = bh / 6, h = bh % 6;
  short* myP = (short*)(lds + 32768 + wv * 2560);  // [32 q][40 shorts] rows 80B

  const short* qbase = qb + (size_t)bh * 131072;
  const char*  kgl   = (const char*)(kb + (size_t)bh * 131072);
  const char*  vgl   = (const char*)(vT + (size_t)bh * 131072);
  const int q0 = qt * 64 + wv * 32;

  bf16x8 qf[2][4];   // hoisted Q: 32 rows x 128 d per wave
#pragma unroll
  for (int mf = 0; mf < 2; mf++)
#pragma unroll
    for (int dc = 0; dc < 4; dc++)
      qf[mf][dc] = *(const bf16x8*)(qbase + (size_t)(q0 + mf*16 + c) * 128 + dc*32 + g*8);

  const float t2 = temp[h] * 1.44269504088896341f;
  const f32x4 z4 = {0.f, 0.f, 0.f, 0.f};
  f32x4 oacc[2][8];
#pragma unroll
  for (int i = 0; i < 2; i++)
#pragma unroll
    for (int j = 0; j < 8; j++) oacc[i][j] = z4;
  float lsum[2][4] = {{0.f,0.f,0.f,0.f},{0.f,0.f,0.f,0.f}};

  // stage K[kt..kt+32)x128d (8KB, swz ((row&7)<<4)) and V^T 128d x [kt..kt+32)
  // (8KB, swz (((d>>1)&3)<<4)) into parity p. 8 loads/lane, contiguous 1KB chunks.
  auto STAGE = [&](int kt, int p) {
    char* kbuf = lds + p * 16384;
    char* vbuf = kbuf + 8192;
#pragma unroll
    for (int i = 0; i < 4; i++) {
      const int ob_ = (i * 2 + wv) * 1024;          // 8 x 1024B = full 8KB
      const int o = ob_ + lane * 16;
      {
        const int row = o >> 8;                     // K: rows 256B
        const int cb = (o & 255) ^ ((row & 7) << 4);
        gload16(kgl + (size_t)(kt + row) * 256 + cb, kbuf + ob_);
      }
      {
        const int d = o >> 6;                       // V^T: rows 64B
        const int cb = (o & 63) ^ (((d >> 1) & 3) << 4);
        gload16(vgl + (size_t)d * 2048 + (size_t)kt * 2 + cb, vbuf + ob_);
      }
    }
  };
  auto COMPUTE = [&](int p) {
    char* kbuf = lds + p * 16384;
    char* vbuf = kbuf + 8192;
    f32x4 s[2][2];
#pragma unroll
    for (int i = 0; i < 2; i++)
#pragma unroll
      for (int j = 0; j < 2; j++) s[i][j] = z4;
#pragma unroll
    for (int kf = 0; kf < 2; kf++) {
      bf16x8 kfr[4];
#pragma unroll
      for (int kc = 0; kc < 4; kc++) {
        const int row = kf * 16 + c;
        kfr[kc] = *(const bf16x8*)(kbuf + row * 256 + ((kc * 64 + g * 16) ^ ((row & 7) << 4)));
      }
      __builtin_amdgcn_s_setprio(1);
#pragma unroll
      for (int kc = 0; kc < 4; kc++) {
        s[0][kf] = MFMA16(qf[0][kc], kfr[kc], s[0][kf]);
        s[1][kf] = MFMA16(qf[1][kc], kfr[kc], s[1][kf]);
      }
      __builtin_amdgcn_s_setprio(0);
    }
#pragma unroll
    for (int mf = 0; mf < 2; mf++)
#pragma unroll
      for (int kf = 0; kf < 2; kf++)
#pragma unroll
        for (int r = 0; r < 4; r++) {
          float pv = __builtin_amdgcn_exp2f(s[mf][kf][r] * t2);
          lsum[mf][r] += pv;
          myP[(mf*16 + 4*g + r) * 40 + kf*16 + c] = f2bf(pv);
        }
    bf16x8 pa0 = *(const bf16x8*)&myP[(c)      * 40 + g*8];
    bf16x8 pa1 = *(const bf16x8*)&myP[(16 + c) * 40 + g*8];
    __builtin_amdgcn_s_setprio(1);
#pragma unroll
    for (int df = 0; df < 8; df++) {
      const int d = df * 16 + c;
      bf16x8 vf = *(const bf16x8*)(vbuf + d * 64 + ((g * 16) ^ (((d >> 1) & 3) << 4)));
      oacc[0][df] = MFMA16(pa0, vf, oacc[0][df]);
      oacc[1][df] = MFMA16(pa1, vf, oacc[1][df]);
    }
    __builtin_amdgcn_s_setprio(0);
  };

  STAGE(0, 0);
  WAITV(0); BAR();
  for (int it = 0; it < 31; it++) {
    STAGE((it + 1) * 32, (it + 1) & 1);
    WAITV(8); BAR();
    COMPUTE(it & 1);
    BAR();
  }
  WAITV(0); BAR();
  COMPUTE(1);

  // finalize: row sums -> 1/sum, normalize O, stage via LDS (staging region), store
  float rin[2][4];
#pragma unroll
  for (int mf = 0; mf < 2; mf++)
#pragma unroll
    for (int r = 0; r < 4; r++) {
      float s = lsum[mf][r];
      s += __shfl_xor(s, 1); s += __shfl_xor(s, 2);
      s += __shfl_xor(s, 4); s += __shfl_xor(s, 8);
      rin[mf][r] = 1.0f / s;
    }
  __syncthreads();   // all waves done with final tile reads; staging region reusable
  short* myO = (short*)(lds + wv * 8704);   // 32x136 shorts, wave-private
#pragma unroll
  for (int mf = 0; mf < 2; mf++)
#pragma unroll
    for (int df = 0; df < 8; df++)
#pragma unroll
      for (int r = 0; r < 4; r++)
        myO[(mf*16 + 4*g + r) * 136 + df*16 + c] = f2bf(oacc[mf][df][r] * rin[mf][r]);
  const size_t obase_ = ((size_t)(b * 1024 + q0)) * 768 + h * 128;
#pragma unroll
  for (int it = 0; it < 8; it++) {
    const int slot = it * 64 + lane;
    const int row = slot >> 4, ch = slot & 15;
    bf16x8 v = *(const bf16x8*)&myO[row * 136 + ch * 8];
    *(bf16x8*)(ob + obase_ + (size_t)row * 768 + ch * 8) = v;
  }
}

// ---------------- output projection GEMM v2: dbuf + counted vmcnt + T2 swizzle -----
__global__ __launch_bounds__(256, 2) void proj_gemm(
    const short* __restrict__ ob, const short* __restrict__ wpb,
    const float* __restrict__ bias, float* __restrict__ out)
{
  __shared__ __align__(16) char lds[65536];
  const int t = threadIdx.x;
  const int wv = t >> 6, lane = t & 63;
  const int c = lane & 15, g = lane >> 4;
  const int wm = wv >> 1, wn = wv & 1;
  const int bm = blockIdx.x, bn = blockIdx.y;
  const short* W = wpb + (size_t)bn * 98304;
  const int am0 = bm * 128;
  const f32x4 z4 = {0.f, 0.f, 0.f, 0.f};
  f32x4 acc[4][4];
#pragma unroll
  for (int i = 0; i < 4; i++)
#pragma unroll
    for (int j = 0; j < 4; j++) acc[i][j] = z4;

  auto STAGE = [&](int kt, int p) {
    char* lA = lds + p * 32768;
    char* lB = lA + 16384;
#pragma unroll
    for (int i = 0; i < 4; i++) {
      const int ob_ = (i * 4 + wv) * 1024;
      const int o = ob_ + lane * 16;
      const int row = o >> 7;
      const int cb = (o & 127) ^ ((row & 7) << 4);
      gload16((const char*)ob + ((size_t)(am0 + row) * 768 + kt) * 2 + cb, lA + ob_);
      gload16((const char*)W  + ((size_t)row * 768 + kt) * 2 + cb, lB + ob_);
    }
  };
  auto COMPUTE = [&](int p) {
    char* lA = lds + p * 32768;
    char* lB = lA + 16384;
#pragma unroll
    for (int kc = 0; kc < 2; kc++) {
      bf16x8 af[4], bfr[4];
#pragma unroll
      for (int mf = 0; mf < 4; mf++) {
        const int row = wm * 64 + mf * 16 + c;
        af[mf] = *(const bf16x8*)(lA + row * 128 + ((kc * 64 + g * 16) ^ ((row & 7) << 4)));
      }
#pragma unroll
      for (int nf = 0; nf < 4; nf++) {
        const int row = wn * 64 + nf * 16 + c;
        bfr[nf] = *(const bf16x8*)(lB + row * 128 + ((kc * 64 + g * 16) ^ ((row & 7) << 4)));
      }
      __builtin_amdgcn_s_setprio(1);
#pragma unroll
      for (int mf = 0; mf < 4; mf++)
#pragma unroll
        for (int nf = 0; nf < 4; nf++)
          acc[mf][nf] = MFMA16(af[mf], bfr[nf], acc[mf][nf]);
      __builtin_amdgcn_s_setprio(0);
    }
  };

  STAGE(0, 0);
  WAITV(0); BAR();
  for (int kt = 0; kt < 11; kt++) {
    STAGE((kt + 1) * 64, (kt + 1) & 1);
    WAITV(8); BAR();
    COMPUTE(kt & 1);
    BAR();
  }
  WAITV(0); BAR();
  COMPUTE(1);

  float bb[4];
#pragma unroll
  for (int nf = 0; nf < 4; nf++) bb[nf] = bias[bn*128 + wn*64 + nf*16 + c];
#pragma unroll
  for (int mf = 0; mf < 4; mf++)
#pragma unroll
    for (int nf = 0; nf < 4; nf++)
#pragma unroll
      for (int r = 0; r < 4; r++)
        out[(size_t)(am0 + wm*64 + mf*16 + 4*g + r) * 768 + bn*128 + wn*64 + nf*16 + c]
            = acc[mf][nf][r] + bb[nf];
}

extern "C" void kernel_launch(void* const* d_in, const int* in_sizes, int n_in,
                              void* d_out, int out_size, void* d_ws, size_t ws_size,
                              hipStream_t stream) {
  const float* x    = (const float*)d_in[0];
  const float* y    = (const float*)d_in[1];
  const float* wq   = (const float*)d_in[2];
  const float* wkv  = (const float*)d_in[3];
  const float* wp   = (const float*)d_in[4];
  const float* bias = (const float*)d_in[5];
  const float* temp = (const float*)d_in[6];

  short* ws   = (short*)d_ws;
  short* xb   = ws;
  short* yb   = xb + 6291456;
  short* wqb  = yb + 6291456;
  short* wkvb = wqb + 589824;
  short* wpb  = wkvb + 1179648;
  short* qb   = wpb + 589824;
  short* kb   = qb + 6291456;
  short* vT   = kb + 6291456;
  short* ob   = vT + 6291456;

  convert_all<<<dim3(1024), dim3(256), 0, stream>>>(x, y, wq, wkv, wp, ws);
  qkv_gemm<<<dim3(64, 18), dim3(256), 0, stream>>>(xb, yb, wqb, wkvb, qb, kb, vT);
  attn_fwd<<<dim3(768), dim3(128), 0, stream>>>(qb, kb, vT, temp, ob);
  proj_gemm<<<dim3(64, 6), dim3(256), 0, stream>>>(ob, wpb, bias, (float*)d_out);
}